// Round 6
// baseline (1109.862 us; speedup 1.0000x reference)
//
#include <hip/hip_runtime.h>

// GHM_68143951118654 — v12: exact v7 kernels (session best, 1073.9 µs).
// Single change: s_partial grid 512->768 (3 blocks/CU, LDS 138/160 KB),
// keeping v7's issue-after-barrier discipline (v9's regression was the
// issue-before-barrier move, not the grid). Spart(768) aliased on dead TX.

typedef unsigned short u16;
typedef unsigned int u32;
typedef short bf16x8 __attribute__((ext_vector_type(8)));
typedef float f32x4 __attribute__((ext_vector_type(4)));

__device__ __forceinline__ float gelu_f(float x) {
  float s = x * x;
  float z = x * fmaf(s, -0.10294348f, -2.3022077f);   // -(log2e)*(c1 x^2 + c0)
  float e = __builtin_amdgcn_exp2f(z);
  return x * __builtin_amdgcn_rcpf(1.0f + e);
}
__device__ __forceinline__ u16 f2b(float f) {
  union { float f; unsigned u; } v; v.f = f;
  unsigned u = v.u;
  u += 0x7fffu + ((u >> 16) & 1u);   // round-to-nearest-even
  return (u16)(u >> 16);
}
__device__ __forceinline__ float b2f(u16 b) {
  union { float f; u32 u; } v; v.u = (u32)b << 16;
  return v.f;
}
// XOR-swizzled 64xK tile offset (u16 elements): row-major 256/row, the 16B
// unit index has its low 3 bits XORed with (row&7) -> b128 reads are ~2-way.
__device__ __forceinline__ int swz(int row, int col) {
  return row * 256 + (((col >> 3) ^ (row & 7)) << 3) + (col & 7);
}

// ---------------------------------------------------------------------------
// Weight prep: fp32 -> bf16, transposed to [out][in].
// ---------------------------------------------------------------------------
__global__ __launch_bounds__(256) void prep_weights(
    const float* __restrict__ s0, const float* __restrict__ s1,
    const float* __restrict__ s2, const float* __restrict__ s3,
    const float* __restrict__ s4, const float* __restrict__ s5,
    const float* __restrict__ s6, const float* __restrict__ s7,
    u16* __restrict__ dst)
{
  int idx = blockIdx.x * 256 + threadIdx.x;
  if (idx >= 557056) return;
  const float* src; int base, R, C;
  if (idx < 278528) {
    if (idx < 131072) {
      if (idx < 65536) { base = 0;      src = s0; R = 256; C = 256; }
      else             { base = 65536;  src = s1; R = 256; C = 256; }
    } else {
      if (idx < 147456){ base = 131072; src = s2; R = 256; C = 64;  }
      else             { base = 147456; src = s3; R = 512; C = 256; }
    }
  } else {
    int j = idx - 278528;
    if (j < 131072) {
      if (j < 65536)   { base = 278528; src = s4; R = 256; C = 256; }
      else             { base = 344064; src = s5; R = 256; C = 256; }
    } else {
      if (j < 147456)  { base = 409600; src = s6; R = 256; C = 64;  }
      else             { base = 425984; src = s7; R = 512; C = 256; }
    }
  }
  int local = idx - base;
  int o = local / R;
  int k = local - o * R;
  dst[idx] = f2b(src[k * C + o]);   // dst[o][k] = src[k][o]
}

// ---------------------------------------------------------------------------
// Mega: FF1 + hyper. 128 rows/block, 4 waves col-split, B-frag prefetch.
// Epilogues vectorized: global stores go through LDS and out as uint4.
// ---------------------------------------------------------------------------
template<bool AFP32>
__global__ __launch_bounds__(256, 2) void ff1_hyper(
    const void* __restrict__ Av, const u16* __restrict__ W1T,
    const float* __restrict__ bias, const u16* __restrict__ wAT,
    const u16* __restrict__ wBT, u16* __restrict__ Hf,
    u16* __restrict__ Hfg, u16* __restrict__ Wt, int N)
{
  __shared__ u16 Asm[128][264];
  const int tid = threadIdx.x;
  const int wave = tid >> 6, lane = tid & 63;
  int r0 = blockIdx.x * 128;
  if (r0 > N - 128) r0 = N - 128;

  if constexpr (AFP32) {
    const float* A = (const float*)Av;
    #pragma unroll
    for (int j = 0; j < 32; ++j) {
      int idx = j * 256 + tid;
      int row = idx >> 6, c4 = idx & 63;
      float4 v = *(const float4*)(A + (size_t)(r0 + row) * 256 + c4 * 4);
      uint2 p;
      p.x = (u32)f2b(v.x) | ((u32)f2b(v.y) << 16);
      p.y = (u32)f2b(v.z) | ((u32)f2b(v.w) << 16);
      *(uint2*)&Asm[row][c4 * 4] = p;
    }
  } else {
    const u16* A = (const u16*)Av;
    #pragma unroll
    for (int j = 0; j < 16; ++j) {
      int idx = j * 256 + tid;
      int row = idx >> 5, c8 = idx & 31;
      *(uint4*)&Asm[row][c8 * 8] =
          *(const uint4*)(A + (size_t)(r0 + row) * 256 + c8 * 8);
    }
  }
  __syncthreads();

  const int lm = lane & 15, lq = lane >> 4;
  const int n0 = wave * 64;

  // ---- FF1: acc = X @ W1^T (cols n0..n0+63), b prefetched ----
  f32x4 acc[8][4] = {};
  {
    bf16x8 bb[2][4];
    #pragma unroll
    for (int ct = 0; ct < 4; ++ct)
      bb[0][ct] = *(const bf16x8*)(W1T + (size_t)(n0 + ct * 16 + lm) * 256 + lq * 8);
    #pragma unroll
    for (int s = 0; s < 8; ++s) {
      const int cur = s & 1;
      if (s < 7)
        #pragma unroll
        for (int ct = 0; ct < 4; ++ct)
          bb[cur ^ 1][ct] = *(const bf16x8*)(W1T + (size_t)(n0 + ct * 16 + lm) * 256 + (s + 1) * 32 + lq * 8);
      bf16x8 a[8];
      #pragma unroll
      for (int rt = 0; rt < 8; ++rt)
        a[rt] = *(const bf16x8*)&Asm[rt * 16 + lm][s * 32 + lq * 8];
      #pragma unroll
      for (int rt = 0; rt < 8; ++rt)
        #pragma unroll
        for (int ct = 0; ct < 4; ++ct)
          acc[rt][ct] = __builtin_amdgcn_mfma_f32_16x16x32_bf16(a[rt], bb[cur][ct], acc[rt][ct], 0, 0, 0);
    }
  }
  __syncthreads();   // done reading X tile

  // ---- FF1 epilogue: Hf -> Asm (scalar, LDS only) ----
  {
    float bv[4];
    #pragma unroll
    for (int ct = 0; ct < 4; ++ct) bv[ct] = bias[n0 + ct * 16 + lm];
    #pragma unroll
    for (int rt = 0; rt < 8; ++rt)
      #pragma unroll
      for (int ct = 0; ct < 4; ++ct)
        #pragma unroll
        for (int rg = 0; rg < 4; ++rg) {
          float g = gelu_f(acc[rt][ct][rg] + bv[ct]);
          Asm[rt * 16 + lq * 4 + rg][n0 + ct * 16 + lm] = f2b(g);
        }
  }
  __syncthreads();   // Asm = Hf complete

  // ---- vectorized Hf / Hfg writeback (coalesced uint4 stores) ----
  #pragma unroll
  for (int j = 0; j < 16; ++j) {
    int idx = j * 256 + tid;
    int row = idx >> 5, c8 = idx & 31;
    uint4 v = *(const uint4*)&Asm[row][c8 * 8];
    *(uint4*)(Hf + (size_t)(r0 + row) * 256 + c8 * 8) = v;
    u32 wsv[4] = {v.x, v.y, v.z, v.w};
    uint4 go;
    u32* gp = (u32*)&go;
    #pragma unroll
    for (int t = 0; t < 4; ++t) {
      float lo = gelu_f(b2f((u16)(wsv[t] & 0xFFFFu)));
      float hi = gelu_f(b2f((u16)(wsv[t] >> 16)));
      gp[t] = (u32)f2b(lo) | ((u32)f2b(hi) << 16);
    }
    *(uint4*)(Hfg + (size_t)(r0 + row) * 256 + c8 * 8) = go;
  }

  // ---- T = gelu(Hf @ wA^T), b prefetched ----
  #pragma unroll
  for (int rt = 0; rt < 8; ++rt)
    #pragma unroll
    for (int ct = 0; ct < 4; ++ct)
      acc[rt][ct] = (f32x4){0.f, 0.f, 0.f, 0.f};
  {
    bf16x8 bb[2][4];
    #pragma unroll
    for (int ct = 0; ct < 4; ++ct)
      bb[0][ct] = *(const bf16x8*)(wAT + (size_t)(n0 + ct * 16 + lm) * 256 + lq * 8);
    #pragma unroll
    for (int s = 0; s < 8; ++s) {
      const int cur = s & 1;
      if (s < 7)
        #pragma unroll
        for (int ct = 0; ct < 4; ++ct)
          bb[cur ^ 1][ct] = *(const bf16x8*)(wAT + (size_t)(n0 + ct * 16 + lm) * 256 + (s + 1) * 32 + lq * 8);
      bf16x8 a[8];
      #pragma unroll
      for (int rt = 0; rt < 8; ++rt)
        a[rt] = *(const bf16x8*)&Asm[rt * 16 + lm][s * 32 + lq * 8];
      #pragma unroll
      for (int rt = 0; rt < 8; ++rt)
        #pragma unroll
        for (int ct = 0; ct < 4; ++ct)
          acc[rt][ct] = __builtin_amdgcn_mfma_f32_16x16x32_bf16(a[rt], bb[cur][ct], acc[rt][ct], 0, 0, 0);
    }
  }
  __syncthreads();   // done reading Hf tile
  #pragma unroll
  for (int rt = 0; rt < 8; ++rt)
    #pragma unroll
    for (int ct = 0; ct < 4; ++ct)
      #pragma unroll
      for (int rg = 0; rg < 4; ++rg)
        Asm[rt * 16 + lq * 4 + rg][n0 + ct * 16 + lm] = f2b(gelu_f(acc[rt][ct][rg]));
  __syncthreads();

  // ---- Wt = T @ wB^T: rows [32*wave, +32), b prefetched ----
  f32x4 acc2[2][4] = {};
  {
    bf16x8 bb[2][4];
    #pragma unroll
    for (int ct = 0; ct < 4; ++ct)
      bb[0][ct] = *(const bf16x8*)(wBT + (size_t)(ct * 16 + lm) * 256 + lq * 8);
    #pragma unroll
    for (int s = 0; s < 8; ++s) {
      const int cur = s & 1;
      if (s < 7)
        #pragma unroll
        for (int ct = 0; ct < 4; ++ct)
          bb[cur ^ 1][ct] = *(const bf16x8*)(wBT + (size_t)(ct * 16 + lm) * 256 + (s + 1) * 32 + lq * 8);
      bf16x8 a[2];
      #pragma unroll
      for (int rt = 0; rt < 2; ++rt)
        a[rt] = *(const bf16x8*)&Asm[wave * 32 + rt * 16 + lm][s * 32 + lq * 8];
      #pragma unroll
      for (int rt = 0; rt < 2; ++rt)
        #pragma unroll
        for (int ct = 0; ct < 4; ++ct)
          acc2[rt][ct] = __builtin_amdgcn_mfma_f32_16x16x32_bf16(a[rt], bb[cur][ct], acc2[rt][ct], 0, 0, 0);
    }
  }
  // Wt epilogue via own (now-dead) Asm slab: scalar LDS writes, then
  // coalesced uint4 global stores. Same-wave DS ordering -> no barrier.
  #pragma unroll
  for (int rt = 0; rt < 2; ++rt)
    #pragma unroll
    for (int ct = 0; ct < 4; ++ct)
      #pragma unroll
      for (int rg = 0; rg < 4; ++rg)
        Asm[wave * 32 + rt * 16 + lq * 4 + rg][ct * 16 + lm] = f2b(acc2[rt][ct][rg]);
  #pragma unroll
  for (int t = 0; t < 4; ++t) {
    int u = t * 64 + lane;
    int rl = u >> 3, c8 = u & 7;
    *(uint4*)(Wt + (size_t)(r0 + wave * 32 + rl) * 64 + c8 * 8) =
        *(const uint4*)&Asm[wave * 32 + rl][c8 * 8];
  }
}

// ---------------------------------------------------------------------------
// S partials, software-pipelined (v7 discipline: issue AFTER the barrier).
// Grid 768 -> 3 blocks/CU (LDS 138/160 KB) for deeper latency hiding.
// ---------------------------------------------------------------------------
__global__ __launch_bounds__(256) void s_partial_v2(
    const u16* __restrict__ Hf, const u16* __restrict__ Wt,
    float* __restrict__ Spart, int N)
{
  __shared__ u16 HfT[256][72];
  __shared__ u16 WtT[64][72];
  const int tid = threadIdx.x;
  const int wave = tid >> 6, lane = tid & 63;
  const int lm = lane & 15, lq = lane >> 4;
  const int rp = tid & 31;
  const int mb = tid >> 5;
  uint4 hx[4][2], wx[2];
  auto issue = [&](int ch) {
    int i0 = ch << 6;
    #pragma unroll
    for (int q = 0; q < 4; ++q) {
      const u16* px = Hf + (size_t)(i0 + 2 * rp) * 256 + (mb + 8 * q) * 8;
      hx[q][0] = *(const uint4*)px;
      hx[q][1] = *(const uint4*)(px + 256);
    }
    const u16* pw = Wt + (size_t)(i0 + 2 * rp) * 64 + mb * 8;
    wx[0] = *(const uint4*)pw;
    wx[1] = *(const uint4*)(pw + 64);
  };
  f32x4 acc[4][4] = {};
  const int nchunk = N >> 6;
  int ch = blockIdx.x;
  if (ch < nchunk) issue(ch);
  for (; ch < nchunk; ch += gridDim.x) {
    __syncthreads();   // prior MFMA done reading LDS
    #pragma unroll
    for (int q = 0; q < 4; ++q) {
      int m = mb + 8 * q;
      u32 xs[4] = {hx[q][0].x, hx[q][0].y, hx[q][0].z, hx[q][0].w};
      u32 ys[4] = {hx[q][1].x, hx[q][1].y, hx[q][1].z, hx[q][1].w};
      #pragma unroll
      for (int t = 0; t < 4; ++t) {
        *(u32*)&HfT[m * 8 + 2 * t][2 * rp]     = (xs[t] & 0xFFFFu) | (ys[t] << 16);
        *(u32*)&HfT[m * 8 + 2 * t + 1][2 * rp] = (xs[t] >> 16) | (ys[t] & 0xFFFF0000u);
      }
    }
    {
      u32 xs[4] = {wx[0].x, wx[0].y, wx[0].z, wx[0].w};
      u32 ys[4] = {wx[1].x, wx[1].y, wx[1].z, wx[1].w};
      #pragma unroll
      for (int t = 0; t < 4; ++t) {
        *(u32*)&WtT[mb * 8 + 2 * t][2 * rp]     = (xs[t] & 0xFFFFu) | (ys[t] << 16);
        *(u32*)&WtT[mb * 8 + 2 * t + 1][2 * rp] = (xs[t] >> 16) | (ys[t] & 0xFFFF0000u);
      }
    }
    __syncthreads();
    if (ch + (int)gridDim.x < nchunk) issue(ch + (int)gridDim.x);
    #pragma unroll
    for (int k0 = 0; k0 < 64; k0 += 32) {
      bf16x8 a[4], b[4];
      #pragma unroll
      for (int t = 0; t < 4; ++t)
        a[t] = *(const bf16x8*)&HfT[wave * 64 + t * 16 + lm][k0 + lq * 8];
      #pragma unroll
      for (int m = 0; m < 4; ++m)
        b[m] = *(const bf16x8*)&WtT[m * 16 + lm][k0 + lq * 8];
      #pragma unroll
      for (int t = 0; t < 4; ++t)
        #pragma unroll
        for (int m = 0; m < 4; ++m)
          acc[t][m] = __builtin_amdgcn_mfma_f32_16x16x32_bf16(a[t], b[m], acc[t][m], 0, 0, 0);
    }
  }
  float* out = Spart + (size_t)blockIdx.x * 16384;
  #pragma unroll
  for (int t = 0; t < 4; ++t)
    #pragma unroll
    for (int m = 0; m < 4; ++m)
      #pragma unroll
      for (int rg = 0; rg < 4; ++rg)
        out[(size_t)(wave * 64 + t * 16 + lq * 4 + rg) * 64 + m * 16 + lm] = acc[t][m][rg];
}

__global__ __launch_bounds__(256) void s_reduce(
    const float* __restrict__ Spart, u16* __restrict__ agg, int nparts)
{
  int e = blockIdx.x * 256 + threadIdx.x;
  float s0 = 0.f, s1 = 0.f, s2 = 0.f, s3 = 0.f;
  for (int p = 0; p < nparts; p += 4) {
    s0 += Spart[(size_t)(p + 0) * 16384 + e];
    s1 += Spart[(size_t)(p + 1) * 16384 + e];
    s2 += Spart[(size_t)(p + 2) * 16384 + e];
    s3 += Spart[(size_t)(p + 3) * 16384 + e];
  }
  agg[e] = f2b(gelu_f((s0 + s1) + (s2 + s3)));
}

// ---------------------------------------------------------------------------
// Fused: async global_load_lds stages the 64x256 Hfg tile (swizzled LDS);
// stage1 P = gelu(Wt@agg^T) -> swizzled LDS; stage2 fully-unrolled K=512 with
// depth-2 W2T (L2) prefetch + double-buffered A frags; first two B-loads
// hoisted above stage 1 so their latency hides under the P GEMM.
// ---------------------------------------------------------------------------
template<bool COLSUM>
__global__ __launch_bounds__(256, 2) void fused_p_ff2_v6(
    const u16* __restrict__ Wt, const u16* __restrict__ agg,
    const u16* __restrict__ Hfg, const u16* __restrict__ W2T,
    const float* __restrict__ bias, u16* __restrict__ X,
    float* __restrict__ colsum, int N)
{
  __shared__ u16 Hsm[64 * 256];   // swizzled gelu(Hf) tile (32 KB)
  __shared__ u16 Pl[64 * 256];    // swizzled P tile (32 KB)
  const int tid = threadIdx.x;
  const int wave = tid >> 6, lane = tid & 63;
  const int lm = lane & 15, lq = lane >> 4;
  const int r0 = blockIdx.x * 64;   // N % 64 == 0
  const int n0 = wave * 64;

  // async stage Hfg tile -> LDS, 8 x 1KB per wave, swizzle-consistent
  #pragma unroll
  for (int t = 0; t < 8; ++t) {
    int unit = (wave * 8 + t) * 64 + lane;   // 16B units, row-major swizzled
    int row = unit >> 5, ksw = unit & 31;
    int kc = ksw ^ (row & 7);
    const u16* g = Hfg + (size_t)(r0 + row) * 256 + kc * 8;
    __builtin_amdgcn_global_load_lds(
        (const __attribute__((address_space(1))) void*)g,
        (__attribute__((address_space(3))) void*)(Hsm + (size_t)(wave * 8 + t) * 512),
        16, 0, 0);
  }

  auto ldb = [&](int s, bf16x8* b) {
    #pragma unroll
    for (int ct = 0; ct < 4; ++ct)
      b[ct] = *(const bf16x8*)(W2T + (size_t)(n0 + ct * 16 + lm) * 512 + s * 32 + lq * 8);
  };
  auto lda = [&](int s, bf16x8* a) {
    const u16* base = (s < 8) ? Pl : Hsm;
    const int k0 = (s & 7) * 32;
    #pragma unroll
    for (int rt = 0; rt < 4; ++rt) {
      int row = rt * 16 + lm;
      a[rt] = *(const bf16x8*)&base[swz(row, k0 + lq * 8)];
    }
  };

  bf16x8 bb[3][4];
  ldb(0, bb[0]);   // in flight under stage 1
  ldb(1, bb[1]);

  // stage 1: P cols [n0, n0+64) -> swizzled Pl
  {
    f32x4 acc[4][4] = {};
    #pragma unroll
    for (int k0 = 0; k0 < 64; k0 += 32) {
      bf16x8 a[4], b[4];
      #pragma unroll
      for (int ct = 0; ct < 4; ++ct)
        b[ct] = *(const bf16x8*)(agg + (size_t)(n0 + ct * 16 + lm) * 64 + k0 + lq * 8);
      #pragma unroll
      for (int rt = 0; rt < 4; ++rt)
        a[rt] = *(const bf16x8*)(Wt + (size_t)(r0 + rt * 16 + lm) * 64 + k0 + lq * 8);
      #pragma unroll
      for (int rt = 0; rt < 4; ++rt)
        #pragma unroll
        for (int ct = 0; ct < 4; ++ct)
          acc[rt][ct] = __builtin_amdgcn_mfma_f32_16x16x32_bf16(a[rt], b[ct], acc[rt][ct], 0, 0, 0);
    }
    #pragma unroll
    for (int rt = 0; rt < 4; ++rt)
      #pragma unroll
      for (int ct = 0; ct < 4; ++ct)
        #pragma unroll
        for (int rg = 0; rg < 4; ++rg)
          Pl[swz(rt * 16 + lq * 4 + rg, n0 + ct * 16 + lm)] = f2b(gelu_f(acc[rt][ct][rg]));
  }
  __syncthreads();   // drains global_load_lds too

  // stage 2: X = [P | Hfg] @ W2T + b, fully unrolled, depth-2 B prefetch
  f32x4 acc[4][4] = {};
  bf16x8 ab[2][4];
  lda(0, ab[0]);
  #pragma unroll
  for (int s = 0; s < 16; ++s) {
    const int cur = s & 1, nxt = cur ^ 1;
    if (s < 14) ldb(s + 2, bb[(s + 2) % 3]);
    if (s < 15) lda(s + 1, ab[nxt]);
    #pragma unroll
    for (int rt = 0; rt < 4; ++rt)
      #pragma unroll
      for (int ct = 0; ct < 4; ++ct)
        acc[rt][ct] = __builtin_amdgcn_mfma_f32_16x16x32_bf16(ab[cur][rt], bb[s % 3][ct], acc[rt][ct], 0, 0, 0);
  }
  float bv[4];
  #pragma unroll
  for (int ct = 0; ct < 4; ++ct) bv[ct] = bias[n0 + ct * 16 + lm];
  if constexpr (!COLSUM) {
    #pragma unroll
    for (int rt = 0; rt < 4; ++rt)
      #pragma unroll
      for (int ct = 0; ct < 4; ++ct)
        #pragma unroll
        for (int rg = 0; rg < 4; ++rg)
          X[(size_t)(r0 + rt * 16 + lq * 4 + rg) * 256 + n0 + ct * 16 + lm] =
              f2b(acc[rt][ct][rg] + bv[ct]);
  } else {
    #pragma unroll
    for (int ct = 0; ct < 4; ++ct) {
      float cs = 0.0f;
      #pragma unroll
      for (int rt = 0; rt < 4; ++rt)
        #pragma unroll
        for (int rg = 0; rg < 4; ++rg) cs += acc[rt][ct][rg] + bv[ct];
      cs += __shfl_down(cs, 32);
      cs += __shfl_down(cs, 16);
      if (lq == 0) atomicAdd(&colsum[n0 + ct * 16 + lm], cs);
    }
  }
}

__global__ __launch_bounds__(64) void head_kernel(
    const float* __restrict__ colsum, const float* __restrict__ head_w,
    const float* __restrict__ head_b, float* __restrict__ out, float invN)
{
  const int c = threadIdx.x;
  float s = head_b[c];
  for (int h = 0; h < 256; ++h) s = fmaf(colsum[h] * invN, head_w[h * 64 + c], s);
  out[c] = s;
}

// ---------------------------------------------------------------------------
extern "C" void kernel_launch(void* const* d_in, const int* in_sizes, int n_in,
                              void* d_out, int out_size, void* d_ws, size_t ws_size,
                              hipStream_t stream)
{
  const float* x        = (const float*)d_in[0];
  const float* ff1_w[2] = {(const float*)d_in[2],  (const float*)d_in[8]};
  const float* ff1_b[2] = {(const float*)d_in[3],  (const float*)d_in[9]};
  const float* wA[2]    = {(const float*)d_in[4],  (const float*)d_in[10]};
  const float* wB[2]    = {(const float*)d_in[5],  (const float*)d_in[11]};
  const float* ff2_w[2] = {(const float*)d_in[6],  (const float*)d_in[12]};
  const float* ff2_b[2] = {(const float*)d_in[7],  (const float*)d_in[13]};
  const float* head_w   = (const float*)d_in[14];
  const float* head_b   = (const float*)d_in[15];
  const int N = in_sizes[0] / 256;   // 200000

  char* ws = (char*)d_ws;
  u16* WT = (u16*)ws;
  u16* W1T[2] = {WT + 0,      WT + 278528};
  u16* wAT[2] = {WT + 65536,  WT + 344064};
  u16* wBT[2] = {WT + 131072, WT + 409600};
  u16* W2T[2] = {WT + 147456, WT + 425984};
  size_t o = 1114112;
  u16* Hf  = (u16*)(ws + o); o += (size_t)N * 256 * 2;
  u16* Hfg = (u16*)(ws + o); o += (size_t)N * 256 * 2;
  u16* TX  = (u16*)(ws + o); o += (size_t)N * 256 * 2;
  u16* Wt  = (u16*)(ws + o); o += (size_t)N * 64 * 2;
  u16*   agg    = (u16*)(ws + o);   o += 16384 * 2;
  float* colsum = (float*)(ws + o); o += 256 * 4;
  // Spart (768 x 16384 f32 = 50.3 MB) aliases TX (102.4 MB): TX is written
  // by fused only after s_reduce has consumed Spart, and is dead again once
  // the next ff1 has read it — no lifetime overlap.
  float* Spart = (float*)TX;
  const int NPARTS = 768;
  (void)ws_size; (void)n_in; (void)out_size;

  hipMemsetAsync(colsum, 0, 256 * sizeof(float), stream);
  prep_weights<<<2176, 256, 0, stream>>>(ff1_w[0], wA[0], wB[0], ff2_w[0],
                                         ff1_w[1], wA[1], wB[1], ff2_w[1], WT);
  const int G128 = (N + 127) / 128;   // last block clamps r0
  const int G64  = N / 64;
  // block 0
  ff1_hyper<true><<<G128, 256, 0, stream>>>(x, W1T[0], ff1_b[0], wAT[0], wBT[0], Hf, Hfg, Wt, N);
  s_partial_v2<<<NPARTS, 256, 0, stream>>>(Hf, Wt, Spart, N);
  s_reduce<<<64, 256, 0, stream>>>(Spart, agg, NPARTS);
  fused_p_ff2_v6<false><<<G64, 256, 0, stream>>>(Wt, agg, Hfg, W2T[0], ff2_b[0], TX, nullptr, N);
  // block 1
  ff1_hyper<false><<<G128, 256, 0, stream>>>(TX, W1T[1], ff1_b[1], wAT[1], wBT[1], Hf, Hfg, Wt, N);
  s_partial_v2<<<NPARTS, 256, 0, stream>>>(Hf, Wt, Spart, N);
  s_reduce<<<64, 256, 0, stream>>>(Spart, agg, NPARTS);
  fused_p_ff2_v6<true><<<G64, 256, 0, stream>>>(Wt, agg, Hfg, W2T[1], ff2_b[1], nullptr, colsum, N);
  head_kernel<<<1, 64, 0, stream>>>(colsum, head_w, head_b, (float*)d_out, 1.0f / (float)N);
}

// Round 7
// 1016.590 us; speedup vs baseline: 1.0918x; 1.0918x over previous
//
#include <hip/hip_runtime.h>

// GHM_68143951118654 — v13: v7 exact structure; Hfg eliminated. ff1 writes
// only Hf (pure uint4 copy epilogue, -102 MB write, -128 gelu/thread);
// fused stages Hf and applies gelu in-place in LDS (64 elems/thread,
// bit-identical to the old Hfg). s_partial/s_reduce exactly v7.

typedef unsigned short u16;
typedef unsigned int u32;
typedef short bf16x8 __attribute__((ext_vector_type(8)));
typedef float f32x4 __attribute__((ext_vector_type(4)));

__device__ __forceinline__ float gelu_f(float x) {
  float s = x * x;
  float z = x * fmaf(s, -0.10294348f, -2.3022077f);   // -(log2e)*(c1 x^2 + c0)
  float e = __builtin_amdgcn_exp2f(z);
  return x * __builtin_amdgcn_rcpf(1.0f + e);
}
__device__ __forceinline__ u16 f2b(float f) {
  union { float f; unsigned u; } v; v.f = f;
  unsigned u = v.u;
  u += 0x7fffu + ((u >> 16) & 1u);   // round-to-nearest-even
  return (u16)(u >> 16);
}
__device__ __forceinline__ float b2f(u16 b) {
  union { float f; u32 u; } v; v.u = (u32)b << 16;
  return v.f;
}
// XOR-swizzled 64xK tile offset (u16 elements): row-major 256/row, the 16B
// unit index has its low 3 bits XORed with (row&7) -> b128 reads are ~2-way.
__device__ __forceinline__ int swz(int row, int col) {
  return row * 256 + (((col >> 3) ^ (row & 7)) << 3) + (col & 7);
}

// ---------------------------------------------------------------------------
// Weight prep: fp32 -> bf16, transposed to [out][in].
// ---------------------------------------------------------------------------
__global__ __launch_bounds__(256) void prep_weights(
    const float* __restrict__ s0, const float* __restrict__ s1,
    const float* __restrict__ s2, const float* __restrict__ s3,
    const float* __restrict__ s4, const float* __restrict__ s5,
    const float* __restrict__ s6, const float* __restrict__ s7,
    u16* __restrict__ dst)
{
  int idx = blockIdx.x * 256 + threadIdx.x;
  if (idx >= 557056) return;
  const float* src; int base, R, C;
  if (idx < 278528) {
    if (idx < 131072) {
      if (idx < 65536) { base = 0;      src = s0; R = 256; C = 256; }
      else             { base = 65536;  src = s1; R = 256; C = 256; }
    } else {
      if (idx < 147456){ base = 131072; src = s2; R = 256; C = 64;  }
      else             { base = 147456; src = s3; R = 512; C = 256; }
    }
  } else {
    int j = idx - 278528;
    if (j < 131072) {
      if (j < 65536)   { base = 278528; src = s4; R = 256; C = 256; }
      else             { base = 344064; src = s5; R = 256; C = 256; }
    } else {
      if (j < 147456)  { base = 409600; src = s6; R = 256; C = 64;  }
      else             { base = 425984; src = s7; R = 512; C = 256; }
    }
  }
  int local = idx - base;
  int o = local / R;
  int k = local - o * R;
  dst[idx] = f2b(src[k * C + o]);   // dst[o][k] = src[k][o]
}

// ---------------------------------------------------------------------------
// Mega: FF1 + hyper. 128 rows/block, 4 waves col-split, B-frag prefetch.
// Hf epilogue is now a pure LDS->global uint4 copy (no Hfg, no gelu pass).
// ---------------------------------------------------------------------------
template<bool AFP32>
__global__ __launch_bounds__(256, 2) void ff1_hyper(
    const void* __restrict__ Av, const u16* __restrict__ W1T,
    const float* __restrict__ bias, const u16* __restrict__ wAT,
    const u16* __restrict__ wBT, u16* __restrict__ Hf,
    u16* __restrict__ Wt, int N)
{
  __shared__ u16 Asm[128][264];
  const int tid = threadIdx.x;
  const int wave = tid >> 6, lane = tid & 63;
  int r0 = blockIdx.x * 128;
  if (r0 > N - 128) r0 = N - 128;

  if constexpr (AFP32) {
    const float* A = (const float*)Av;
    #pragma unroll
    for (int j = 0; j < 32; ++j) {
      int idx = j * 256 + tid;
      int row = idx >> 6, c4 = idx & 63;
      float4 v = *(const float4*)(A + (size_t)(r0 + row) * 256 + c4 * 4);
      uint2 p;
      p.x = (u32)f2b(v.x) | ((u32)f2b(v.y) << 16);
      p.y = (u32)f2b(v.z) | ((u32)f2b(v.w) << 16);
      *(uint2*)&Asm[row][c4 * 4] = p;
    }
  } else {
    const u16* A = (const u16*)Av;
    #pragma unroll
    for (int j = 0; j < 16; ++j) {
      int idx = j * 256 + tid;
      int row = idx >> 5, c8 = idx & 31;
      *(uint4*)&Asm[row][c8 * 8] =
          *(const uint4*)(A + (size_t)(r0 + row) * 256 + c8 * 8);
    }
  }
  __syncthreads();

  const int lm = lane & 15, lq = lane >> 4;
  const int n0 = wave * 64;

  // ---- FF1: acc = X @ W1^T (cols n0..n0+63), b prefetched ----
  f32x4 acc[8][4] = {};
  {
    bf16x8 bb[2][4];
    #pragma unroll
    for (int ct = 0; ct < 4; ++ct)
      bb[0][ct] = *(const bf16x8*)(W1T + (size_t)(n0 + ct * 16 + lm) * 256 + lq * 8);
    #pragma unroll
    for (int s = 0; s < 8; ++s) {
      const int cur = s & 1;
      if (s < 7)
        #pragma unroll
        for (int ct = 0; ct < 4; ++ct)
          bb[cur ^ 1][ct] = *(const bf16x8*)(W1T + (size_t)(n0 + ct * 16 + lm) * 256 + (s + 1) * 32 + lq * 8);
      bf16x8 a[8];
      #pragma unroll
      for (int rt = 0; rt < 8; ++rt)
        a[rt] = *(const bf16x8*)&Asm[rt * 16 + lm][s * 32 + lq * 8];
      #pragma unroll
      for (int rt = 0; rt < 8; ++rt)
        #pragma unroll
        for (int ct = 0; ct < 4; ++ct)
          acc[rt][ct] = __builtin_amdgcn_mfma_f32_16x16x32_bf16(a[rt], bb[cur][ct], acc[rt][ct], 0, 0, 0);
    }
  }
  __syncthreads();   // done reading X tile

  // ---- FF1 epilogue: Hf -> Asm (scalar, LDS only) ----
  {
    float bv[4];
    #pragma unroll
    for (int ct = 0; ct < 4; ++ct) bv[ct] = bias[n0 + ct * 16 + lm];
    #pragma unroll
    for (int rt = 0; rt < 8; ++rt)
      #pragma unroll
      for (int ct = 0; ct < 4; ++ct)
        #pragma unroll
        for (int rg = 0; rg < 4; ++rg) {
          float g = gelu_f(acc[rt][ct][rg] + bv[ct]);
          Asm[rt * 16 + lq * 4 + rg][n0 + ct * 16 + lm] = f2b(g);
        }
  }
  __syncthreads();   // Asm = Hf complete

  // ---- vectorized Hf writeback (pure coalesced uint4 copy) ----
  #pragma unroll
  for (int j = 0; j < 16; ++j) {
    int idx = j * 256 + tid;
    int row = idx >> 5, c8 = idx & 31;
    *(uint4*)(Hf + (size_t)(r0 + row) * 256 + c8 * 8) =
        *(const uint4*)&Asm[row][c8 * 8];
  }

  // ---- T = gelu(Hf @ wA^T), b prefetched ----
  #pragma unroll
  for (int rt = 0; rt < 8; ++rt)
    #pragma unroll
    for (int ct = 0; ct < 4; ++ct)
      acc[rt][ct] = (f32x4){0.f, 0.f, 0.f, 0.f};
  {
    bf16x8 bb[2][4];
    #pragma unroll
    for (int ct = 0; ct < 4; ++ct)
      bb[0][ct] = *(const bf16x8*)(wAT + (size_t)(n0 + ct * 16 + lm) * 256 + lq * 8);
    #pragma unroll
    for (int s = 0; s < 8; ++s) {
      const int cur = s & 1;
      if (s < 7)
        #pragma unroll
        for (int ct = 0; ct < 4; ++ct)
          bb[cur ^ 1][ct] = *(const bf16x8*)(wAT + (size_t)(n0 + ct * 16 + lm) * 256 + (s + 1) * 32 + lq * 8);
      bf16x8 a[8];
      #pragma unroll
      for (int rt = 0; rt < 8; ++rt)
        a[rt] = *(const bf16x8*)&Asm[rt * 16 + lm][s * 32 + lq * 8];
      #pragma unroll
      for (int rt = 0; rt < 8; ++rt)
        #pragma unroll
        for (int ct = 0; ct < 4; ++ct)
          acc[rt][ct] = __builtin_amdgcn_mfma_f32_16x16x32_bf16(a[rt], bb[cur][ct], acc[rt][ct], 0, 0, 0);
    }
  }
  __syncthreads();   // done reading Hf tile
  #pragma unroll
  for (int rt = 0; rt < 8; ++rt)
    #pragma unroll
    for (int ct = 0; ct < 4; ++ct)
      #pragma unroll
      for (int rg = 0; rg < 4; ++rg)
        Asm[rt * 16 + lq * 4 + rg][n0 + ct * 16 + lm] = f2b(gelu_f(acc[rt][ct][rg]));
  __syncthreads();

  // ---- Wt = T @ wB^T: rows [32*wave, +32), b prefetched ----
  f32x4 acc2[2][4] = {};
  {
    bf16x8 bb[2][4];
    #pragma unroll
    for (int ct = 0; ct < 4; ++ct)
      bb[0][ct] = *(const bf16x8*)(wBT + (size_t)(ct * 16 + lm) * 256 + lq * 8);
    #pragma unroll
    for (int s = 0; s < 8; ++s) {
      const int cur = s & 1;
      if (s < 7)
        #pragma unroll
        for (int ct = 0; ct < 4; ++ct)
          bb[cur ^ 1][ct] = *(const bf16x8*)(wBT + (size_t)(ct * 16 + lm) * 256 + (s + 1) * 32 + lq * 8);
      bf16x8 a[2];
      #pragma unroll
      for (int rt = 0; rt < 2; ++rt)
        a[rt] = *(const bf16x8*)&Asm[wave * 32 + rt * 16 + lm][s * 32 + lq * 8];
      #pragma unroll
      for (int rt = 0; rt < 2; ++rt)
        #pragma unroll
        for (int ct = 0; ct < 4; ++ct)
          acc2[rt][ct] = __builtin_amdgcn_mfma_f32_16x16x32_bf16(a[rt], bb[cur][ct], acc2[rt][ct], 0, 0, 0);
    }
  }
  // Wt epilogue via own (now-dead) Asm slab: scalar LDS writes, then
  // coalesced uint4 global stores. Same-wave DS ordering -> no barrier.
  #pragma unroll
  for (int rt = 0; rt < 2; ++rt)
    #pragma unroll
    for (int ct = 0; ct < 4; ++ct)
      #pragma unroll
      for (int rg = 0; rg < 4; ++rg)
        Asm[wave * 32 + rt * 16 + lq * 4 + rg][ct * 16 + lm] = f2b(acc2[rt][ct][rg]);
  #pragma unroll
  for (int t = 0; t < 4; ++t) {
    int u = t * 64 + lane;
    int rl = u >> 3, c8 = u & 7;
    *(uint4*)(Wt + (size_t)(r0 + wave * 32 + rl) * 64 + c8 * 8) =
        *(const uint4*)&Asm[wave * 32 + rl][c8 * 8];
  }
}

// ---------------------------------------------------------------------------
// S partials, software-pipelined: chunk ch+1's global loads issue AFTER the
// second barrier, so HBM latency hides behind MFMA (exact v7).
// ---------------------------------------------------------------------------
__global__ __launch_bounds__(256) void s_partial_v2(
    const u16* __restrict__ Hf, const u16* __restrict__ Wt,
    float* __restrict__ Spart, int N)
{
  __shared__ u16 HfT[256][72];
  __shared__ u16 WtT[64][72];
  const int tid = threadIdx.x;
  const int wave = tid >> 6, lane = tid & 63;
  const int lm = lane & 15, lq = lane >> 4;
  const int rp = tid & 31;
  const int mb = tid >> 5;
  uint4 hx[4][2], wx[2];
  auto issue = [&](int ch) {
    int i0 = ch << 6;
    #pragma unroll
    for (int q = 0; q < 4; ++q) {
      const u16* px = Hf + (size_t)(i0 + 2 * rp) * 256 + (mb + 8 * q) * 8;
      hx[q][0] = *(const uint4*)px;
      hx[q][1] = *(const uint4*)(px + 256);
    }
    const u16* pw = Wt + (size_t)(i0 + 2 * rp) * 64 + mb * 8;
    wx[0] = *(const uint4*)pw;
    wx[1] = *(const uint4*)(pw + 64);
  };
  f32x4 acc[4][4] = {};
  const int nchunk = N >> 6;
  int ch = blockIdx.x;
  if (ch < nchunk) issue(ch);
  for (; ch < nchunk; ch += gridDim.x) {
    __syncthreads();   // prior MFMA done reading LDS
    #pragma unroll
    for (int q = 0; q < 4; ++q) {
      int m = mb + 8 * q;
      u32 xs[4] = {hx[q][0].x, hx[q][0].y, hx[q][0].z, hx[q][0].w};
      u32 ys[4] = {hx[q][1].x, hx[q][1].y, hx[q][1].z, hx[q][1].w};
      #pragma unroll
      for (int t = 0; t < 4; ++t) {
        *(u32*)&HfT[m * 8 + 2 * t][2 * rp]     = (xs[t] & 0xFFFFu) | (ys[t] << 16);
        *(u32*)&HfT[m * 8 + 2 * t + 1][2 * rp] = (xs[t] >> 16) | (ys[t] & 0xFFFF0000u);
      }
    }
    {
      u32 xs[4] = {wx[0].x, wx[0].y, wx[0].z, wx[0].w};
      u32 ys[4] = {wx[1].x, wx[1].y, wx[1].z, wx[1].w};
      #pragma unroll
      for (int t = 0; t < 4; ++t) {
        *(u32*)&WtT[mb * 8 + 2 * t][2 * rp]     = (xs[t] & 0xFFFFu) | (ys[t] << 16);
        *(u32*)&WtT[mb * 8 + 2 * t + 1][2 * rp] = (xs[t] >> 16) | (ys[t] & 0xFFFF0000u);
      }
    }
    __syncthreads();
    if (ch + (int)gridDim.x < nchunk) issue(ch + (int)gridDim.x);
    #pragma unroll
    for (int k0 = 0; k0 < 64; k0 += 32) {
      bf16x8 a[4], b[4];
      #pragma unroll
      for (int t = 0; t < 4; ++t)
        a[t] = *(const bf16x8*)&HfT[wave * 64 + t * 16 + lm][k0 + lq * 8];
      #pragma unroll
      for (int m = 0; m < 4; ++m)
        b[m] = *(const bf16x8*)&WtT[m * 16 + lm][k0 + lq * 8];
      #pragma unroll
      for (int t = 0; t < 4; ++t)
        #pragma unroll
        for (int m = 0; m < 4; ++m)
          acc[t][m] = __builtin_amdgcn_mfma_f32_16x16x32_bf16(a[t], b[m], acc[t][m], 0, 0, 0);
    }
  }
  float* out = Spart + (size_t)blockIdx.x * 16384;
  #pragma unroll
  for (int t = 0; t < 4; ++t)
    #pragma unroll
    for (int m = 0; m < 4; ++m)
      #pragma unroll
      for (int rg = 0; rg < 4; ++rg)
        out[(size_t)(wave * 64 + t * 16 + lq * 4 + rg) * 64 + m * 16 + lm] = acc[t][m][rg];
}

__global__ __launch_bounds__(256) void s_reduce(
    const float* __restrict__ Spart, u16* __restrict__ agg, int nparts)
{
  int e = blockIdx.x * 256 + threadIdx.x;
  float s0 = 0.f, s1 = 0.f, s2 = 0.f, s3 = 0.f;
  for (int p = 0; p < nparts; p += 4) {
    s0 += Spart[(size_t)(p + 0) * 16384 + e];
    s1 += Spart[(size_t)(p + 1) * 16384 + e];
    s2 += Spart[(size_t)(p + 2) * 16384 + e];
    s3 += Spart[(size_t)(p + 3) * 16384 + e];
  }
  agg[e] = f2b(gelu_f((s0 + s1) + (s2 + s3)));
}

// ---------------------------------------------------------------------------
// Fused: async global_load_lds stages the 64x256 Hf tile (swizzled LDS) and
// gelus it in place (bit-identical to the old Hfg); stage1 P = gelu(Wt@agg^T)
// -> swizzled LDS; stage2 fully-unrolled K=512 with depth-2 W2T prefetch.
// ---------------------------------------------------------------------------
template<bool COLSUM>
__global__ __launch_bounds__(256, 2) void fused_p_ff2_v6(
    const u16* __restrict__ Wt, const u16* __restrict__ agg,
    const u16* __restrict__ Hf, const u16* __restrict__ W2T,
    const float* __restrict__ bias, u16* __restrict__ X,
    float* __restrict__ colsum, int N)
{
  __shared__ u16 Hsm[64 * 256];   // swizzled Hf tile -> gelu'd in place (32 KB)
  __shared__ u16 Pl[64 * 256];    // swizzled P tile (32 KB)
  const int tid = threadIdx.x;
  const int wave = tid >> 6, lane = tid & 63;
  const int lm = lane & 15, lq = lane >> 4;
  const int r0 = blockIdx.x * 64;   // N % 64 == 0
  const int n0 = wave * 64;

  // async stage Hf tile -> LDS, 8 x 1KB per wave, swizzle-consistent
  #pragma unroll
  for (int t = 0; t < 8; ++t) {
    int unit = (wave * 8 + t) * 64 + lane;   // 16B units, row-major swizzled
    int row = unit >> 5, ksw = unit & 31;
    int kc = ksw ^ (row & 7);
    const u16* g = Hf + (size_t)(r0 + row) * 256 + kc * 8;
    __builtin_amdgcn_global_load_lds(
        (const __attribute__((address_space(1))) void*)g,
        (__attribute__((address_space(3))) void*)(Hsm + (size_t)(wave * 8 + t) * 512),
        16, 0, 0);
  }

  auto ldb = [&](int s, bf16x8* b) {
    #pragma unroll
    for (int ct = 0; ct < 4; ++ct)
      b[ct] = *(const bf16x8*)(W2T + (size_t)(n0 + ct * 16 + lm) * 512 + s * 32 + lq * 8);
  };
  auto lda = [&](int s, bf16x8* a) {
    const u16* base = (s < 8) ? Pl : Hsm;
    const int k0 = (s & 7) * 32;
    #pragma unroll
    for (int rt = 0; rt < 4; ++rt) {
      int row = rt * 16 + lm;
      a[rt] = *(const bf16x8*)&base[swz(row, k0 + lq * 8)];
    }
  };

  bf16x8 bb[3][4];
  ldb(0, bb[0]);   // in flight under stage 1
  ldb(1, bb[1]);

  // stage 1: P cols [n0, n0+64) -> swizzled Pl
  {
    f32x4 acc[4][4] = {};
    #pragma unroll
    for (int k0 = 0; k0 < 64; k0 += 32) {
      bf16x8 a[4], b[4];
      #pragma unroll
      for (int ct = 0; ct < 4; ++ct)
        b[ct] = *(const bf16x8*)(agg + (size_t)(n0 + ct * 16 + lm) * 64 + k0 + lq * 8);
      #pragma unroll
      for (int rt = 0; rt < 4; ++rt)
        a[rt] = *(const bf16x8*)(Wt + (size_t)(r0 + rt * 16 + lm) * 64 + k0 + lq * 8);
      #pragma unroll
      for (int rt = 0; rt < 4; ++rt)
        #pragma unroll
        for (int ct = 0; ct < 4; ++ct)
          acc[rt][ct] = __builtin_amdgcn_mfma_f32_16x16x32_bf16(a[rt], b[ct], acc[rt][ct], 0, 0, 0);
    }
    #pragma unroll
    for (int rt = 0; rt < 4; ++rt)
      #pragma unroll
      for (int ct = 0; ct < 4; ++ct)
        #pragma unroll
        for (int rg = 0; rg < 4; ++rg)
          Pl[swz(rt * 16 + lq * 4 + rg, n0 + ct * 16 + lm)] = f2b(gelu_f(acc[rt][ct][rg]));
  }
  __syncthreads();   // drains global_load_lds; Pl visible

  // in-place gelu on the staged Hf tile (elementwise -> swizzle-irrelevant)
  #pragma unroll
  for (int j = 0; j < 4; ++j) {
    int u = j * 256 + tid;            // uint4 index 0..1023
    uint4 v = *(const uint4*)&Hsm[(size_t)u * 8];
    u32* p = (u32*)&v;
    #pragma unroll
    for (int t = 0; t < 4; ++t) {
      float lo = gelu_f(b2f((u16)(p[t] & 0xFFFFu)));
      float hi = gelu_f(b2f((u16)(p[t] >> 16)));
      p[t] = (u32)f2b(lo) | ((u32)f2b(hi) << 16);
    }
    *(uint4*)&Hsm[(size_t)u * 8] = v;
  }
  __syncthreads();   // gelu'd tile visible to all waves

  // stage 2: X = [P | gelu(Hf)] @ W2T + b, fully unrolled, depth-2 B prefetch
  f32x4 acc[4][4] = {};
  bf16x8 ab[2][4];
  lda(0, ab[0]);
  #pragma unroll
  for (int s = 0; s < 16; ++s) {
    const int cur = s & 1, nxt = cur ^ 1;
    if (s < 14) ldb(s + 2, bb[(s + 2) % 3]);
    if (s < 15) lda(s + 1, ab[nxt]);
    #pragma unroll
    for (int rt = 0; rt < 4; ++rt)
      #pragma unroll
      for (int ct = 0; ct < 4; ++ct)
        acc[rt][ct] = __builtin_amdgcn_mfma_f32_16x16x32_bf16(ab[cur][rt], bb[s % 3][ct], acc[rt][ct], 0, 0, 0);
  }
  float bv[4];
  #pragma unroll
  for (int ct = 0; ct < 4; ++ct) bv[ct] = bias[n0 + ct * 16 + lm];
  if constexpr (!COLSUM) {
    #pragma unroll
    for (int rt = 0; rt < 4; ++rt)
      #pragma unroll
      for (int ct = 0; ct < 4; ++ct)
        #pragma unroll
        for (int rg = 0; rg < 4; ++rg)
          X[(size_t)(r0 + rt * 16 + lq * 4 + rg) * 256 + n0 + ct * 16 + lm] =
              f2b(acc[rt][ct][rg] + bv[ct]);
  } else {
    #pragma unroll
    for (int ct = 0; ct < 4; ++ct) {
      float cs = 0.0f;
      #pragma unroll
      for (int rt = 0; rt < 4; ++rt)
        #pragma unroll
        for (int rg = 0; rg < 4; ++rg) cs += acc[rt][ct][rg] + bv[ct];
      cs += __shfl_down(cs, 32);
      cs += __shfl_down(cs, 16);
      if (lq == 0) atomicAdd(&colsum[n0 + ct * 16 + lm], cs);
    }
  }
}

__global__ __launch_bounds__(64) void head_kernel(
    const float* __restrict__ colsum, const float* __restrict__ head_w,
    const float* __restrict__ head_b, float* __restrict__ out, float invN)
{
  const int c = threadIdx.x;
  float s = head_b[c];
  for (int h = 0; h < 256; ++h) s = fmaf(colsum[h] * invN, head_w[h * 64 + c], s);
  out[c] = s;
}

// ---------------------------------------------------------------------------
extern "C" void kernel_launch(void* const* d_in, const int* in_sizes, int n_in,
                              void* d_out, int out_size, void* d_ws, size_t ws_size,
                              hipStream_t stream)
{
  const float* x        = (const float*)d_in[0];
  const float* ff1_w[2] = {(const float*)d_in[2],  (const float*)d_in[8]};
  const float* ff1_b[2] = {(const float*)d_in[3],  (const float*)d_in[9]};
  const float* wA[2]    = {(const float*)d_in[4],  (const float*)d_in[10]};
  const float* wB[2]    = {(const float*)d_in[5],  (const float*)d_in[11]};
  const float* ff2_w[2] = {(const float*)d_in[6],  (const float*)d_in[12]};
  const float* ff2_b[2] = {(const float*)d_in[7],  (const float*)d_in[13]};
  const float* head_w   = (const float*)d_in[14];
  const float* head_b   = (const float*)d_in[15];
  const int N = in_sizes[0] / 256;   // 200000

  char* ws = (char*)d_ws;
  u16* WT = (u16*)ws;
  u16* W1T[2] = {WT + 0,      WT + 278528};
  u16* wAT[2] = {WT + 65536,  WT + 344064};
  u16* wBT[2] = {WT + 131072, WT + 409600};
  u16* W2T[2] = {WT + 147456, WT + 425984};
  size_t o = 1114112;
  u16* Hf  = (u16*)(ws + o); o += (size_t)N * 256 * 2;
  u16* TX  = (u16*)(ws + o); o += (size_t)N * 256 * 2;
  u16* Wt  = (u16*)(ws + o); o += (size_t)N * 64 * 2;
  float* Spart  = (float*)(ws + o); o += (size_t)512 * 16384 * 4;
  u16*   agg    = (u16*)(ws + o);   o += 16384 * 2;
  float* colsum = (float*)(ws + o); o += 256 * 4;
  (void)ws_size; (void)n_in; (void)out_size;

  hipMemsetAsync(colsum, 0, 256 * sizeof(float), stream);
  prep_weights<<<2176, 256, 0, stream>>>(ff1_w[0], wA[0], wB[0], ff2_w[0],
                                         ff1_w[1], wA[1], wB[1], ff2_w[1], WT);
  const int G128 = (N + 127) / 128;   // last block clamps r0
  const int G64  = N / 64;
  // block 0
  ff1_hyper<true><<<G128, 256, 0, stream>>>(x, W1T[0], ff1_b[0], wAT[0], wBT[0], Hf, Wt, N);
  s_partial_v2<<<512, 256, 0, stream>>>(Hf, Wt, Spart, N);
  s_reduce<<<64, 256, 0, stream>>>(Spart, agg, 512);
  fused_p_ff2_v6<false><<<G64, 256, 0, stream>>>(Wt, agg, Hf, W2T[0], ff2_b[0], TX, nullptr, N);
  // block 1
  ff1_hyper<false><<<G128, 256, 0, stream>>>(TX, W1T[1], ff1_b[1], wAT[1], wBT[1], Hf, Wt, N);
  s_partial_v2<<<512, 256, 0, stream>>>(Hf, Wt, Spart, N);
  s_reduce<<<64, 256, 0, stream>>>(Spart, agg, 512);
  fused_p_ff2_v6<true><<<G64, 256, 0, stream>>>(Wt, agg, Hf, W2T[1], ff2_b[1], nullptr, colsum, N);
  head_kernel<<<1, 64, 0, stream>>>(colsum, head_w, head_b, (float*)d_out, 1.0f / (float)N);
}